// Round 1
// baseline (188.474 us; speedup 1.0000x reference)
//
#include <hip/hip_runtime.h>

// Problem constants (from reference)
constexpr int B = 512;
constexpr int D = 2048;
constexpr int C = 10000;
constexpr long long ND = (long long)C * D;      // 20,480,000 center elements

// ---------------------------------------------------------------------------
// K1: copy centers -> out+1 (new_centers), zero out[0] (loss accumulator).
// out+1 is only 4B-aligned; shift the vector window so STORES are 16B-aligned
// (out+4) and LOADS are dword-aligned (centers+3) — gfx950 global dwordx4
// only requires dword alignment.
// ---------------------------------------------------------------------------
__global__ void copy_centers_kernel(const float* __restrict__ centers,
                                    float* __restrict__ out) {
    const long long M = (ND - 3) / 4;           // vectorized float4 count
    long long t = (long long)blockIdx.x * blockDim.x + threadIdx.x;
    if (t == 0) {
        out[0] = 0.0f;                          // loss accumulator
        out[1] = centers[0];
        out[2] = centers[1];
        out[3] = centers[2];
        // tail: elements [3+4M, ND)
        for (long long j = 3 + 4 * M; j < ND; ++j) out[1 + j] = centers[j];
    }
    const float4* src = reinterpret_cast<const float4*>(centers + 3);
    float4*       dst = reinterpret_cast<float4*>(out + 4);
    long long stride = (long long)gridDim.x * blockDim.x;
    for (long long m = t; m < M; m += stride) dst[m] = src[m];
}

// ---------------------------------------------------------------------------
// K2: per-sample occurrence count k and rank r via O(B^2) LDS scan.
// ws[i]     = 0.5^(k-r)  (coefficient of features[i] in final center row)
// ws[B+i]   = (r==0) ? 0.5^k : -1   (rank-0 marker + center decay)
// ---------------------------------------------------------------------------
__global__ void rank_kernel(const int* __restrict__ labels,
                            float* __restrict__ ws) {
    __shared__ int sl[B];
    int i = threadIdx.x;
    sl[i] = labels[i];
    __syncthreads();
    int l = sl[i];
    int k = 0, r = 0;
    for (int j = 0; j < B; ++j) {
        if (sl[j] == l) { ++k; if (j < i) ++r; }
    }
    ws[i]     = exp2f(-(float)(k - r));
    ws[B + i] = (r == 0) ? exp2f(-(float)k) : -1.0f;
}

// ---------------------------------------------------------------------------
// K3: center loss. One block per sample; float4 loads, wave + LDS reduce,
// one atomicAdd into out[0] per block. out[0] was zeroed by K1.
// ---------------------------------------------------------------------------
__global__ void loss_kernel(const float* __restrict__ features,
                            const int* __restrict__ labels,
                            const float* __restrict__ centers,
                            float* __restrict__ out) {
    int i = blockIdx.x;
    int l = labels[i];
    const float4* f = reinterpret_cast<const float4*>(features + (long long)i * D);
    const float4* c = reinterpret_cast<const float4*>(centers + (long long)l * D);
    float s = 0.0f;
    for (int j = threadIdx.x; j < D / 4; j += blockDim.x) {
        float4 a = f[j], b = c[j];
        float d0 = a.x - b.x, d1 = a.y - b.y, d2 = a.z - b.z, d3 = a.w - b.w;
        s += d0 * d0 + d1 * d1 + d2 * d2 + d3 * d3;
    }
    // wave (64-lane) butterfly reduce
    for (int off = 32; off > 0; off >>= 1) s += __shfl_down(s, off);
    __shared__ float wsum[4];
    int lane = threadIdx.x & 63, wv = threadIdx.x >> 6;
    if (lane == 0) wsum[wv] = s;
    __syncthreads();
    if (threadIdx.x == 0) {
        float tot = wsum[0] + wsum[1] + wsum[2] + wsum[3];
        atomicAdd(out, tot * (1.0f / ((float)B * (float)D)));
    }
}

// ---------------------------------------------------------------------------
// K4: rank-0 samples overwrite their label's row with 0.5^k * c0.
// Must complete before K5's atomic adds (separate launch => ordered).
// ---------------------------------------------------------------------------
__global__ void scale_kernel(const int* __restrict__ labels,
                             const float* __restrict__ centers,
                             const float* __restrict__ ws,
                             float* __restrict__ out) {
    int i = blockIdx.x;
    float sc = ws[B + i];
    if (sc < 0.0f) return;                      // not rank-0
    int l = labels[i];
    const float* c = centers + (long long)l * D;
    float*       o = out + 1 + (long long)l * D;
    for (int j = threadIdx.x; j < D; j += blockDim.x) o[j] = sc * c[j];
}

// ---------------------------------------------------------------------------
// K5: every sample atomically adds 0.5^(k-r) * f_i into its label's row.
// ---------------------------------------------------------------------------
__global__ void add_kernel(const int* __restrict__ labels,
                           const float* __restrict__ features,
                           const float* __restrict__ ws,
                           float* __restrict__ out) {
    int i = blockIdx.x;
    float sc = ws[i];
    int l = labels[i];
    const float* f = features + (long long)i * D;
    float*       o = out + 1 + (long long)l * D;
    for (int j = threadIdx.x; j < D; j += blockDim.x)
        atomicAdd(&o[j], sc * f[j]);
}

extern "C" void kernel_launch(void* const* d_in, const int* in_sizes, int n_in,
                              void* d_out, int out_size, void* d_ws, size_t ws_size,
                              hipStream_t stream) {
    const float* features = (const float*)d_in[0];
    const int*   labels   = (const int*)d_in[1];
    const float* centers  = (const float*)d_in[2];
    float*       out      = (float*)d_out;
    float*       ws       = (float*)d_ws;

    copy_centers_kernel<<<2048, 256, 0, stream>>>(centers, out);
    rank_kernel<<<1, B, 0, stream>>>(labels, ws);
    loss_kernel<<<B, 256, 0, stream>>>(features, labels, centers, out);
    scale_kernel<<<B, 256, 0, stream>>>(labels, centers, ws, out);
    add_kernel<<<B, 256, 0, stream>>>(labels, features, ws, out);
}